// Round 14
// baseline (117.139 us; speedup 1.0000x reference)
//
#include <hip/hip_runtime.h>
#include <hip/hip_bf16.h>
#include <math.h>

// Problem constants
#define BATCH 2
#define SEQ   2048
#define EMB   1024
#define NH    16
#define HD    64
#define M_ROWS (BATCH * SEQ)   // 4096

typedef __attribute__((ext_vector_type(8))) short bf16x8;
typedef __attribute__((ext_vector_type(4))) short bf16x4;
typedef __attribute__((ext_vector_type(4))) float f32x4;

#if defined(__has_builtin)
#if __has_builtin(__builtin_amdgcn_mfma_f32_16x16x16bf16_1k)
#define HAVE_MFMA16 1
#endif
#endif
#ifndef HAVE_MFMA16
#define HAVE_MFMA16 0
#endif

// fp32 -> bf16 round-to-nearest-even, raw bits
__device__ __forceinline__ ushort f2bf(float f) {
    unsigned u = __float_as_uint(f);
    unsigned lsb = (u >> 16) & 1u;
    u += 0x7fffu + lsb;
    return (ushort)(u >> 16);
}

// packed f32 pair -> 2 bf16 in one u32 (RNE), single VALU op
__device__ __forceinline__ unsigned cvt_pk_bf16(float lo, float hi) {
    unsigned r;
    asm("v_cvt_pk_bf16_f32 %0, %1, %2" : "=v"(r) : "v"(lo), "v"(hi));
    return r;
}

__device__ __forceinline__ void gload_lds16(const void* g, void* l) {
    __builtin_amdgcn_global_load_lds(
        (const __attribute__((address_space(1))) unsigned int*)g,
        (__attribute__((address_space(3))) unsigned int*)l, 16, 0, 0);
}

// ---------------------------------------------------------------------------
// fused fp32 -> bf16 conversion of x, qkv_w, o_w (outputs contiguous in ws)
// ---------------------------------------------------------------------------
__global__ __launch_bounds__(256) void cvt3_f32_bf16(
    const float* __restrict__ s1, const float* __restrict__ s2,
    const float* __restrict__ s3, ushort* __restrict__ out,
    int n1, int n2)
{
    int i = (blockIdx.x * 256 + threadIdx.x) * 4;
    const float* src;
    int off;
    if (i < n1)            { src = s1; off = i; }
    else if (i < n1 + n2)  { src = s2; off = i - n1; }
    else                   { src = s3; off = i - n1 - n2; }
    float4 v = *reinterpret_cast<const float4*>(&src[off]);
    uint2 pk;
    pk.x = cvt_pk_bf16(v.x, v.y);
    pk.y = cvt_pk_bf16(v.z, v.w);
    *reinterpret_cast<uint2*>(&out[i]) = pk;
}

// ---------------------------------------------------------------------------
// bf16 MFMA GEMM: C[M,N] = A[M,K] * B[N,K]^T + bias[N]
// MODE 0: fp32 output to Cout (O-projection).
// MODE 1: QKV split — cols [0,1024) = Q, scaled by BETA=0.125*log2(e);
//         cols [0,2048) bf16 to qkb (stride 2048);
//         cols [2048,3072) = V written TRANSPOSED to vtb[b*16+h][d][t].
// ---------------------------------------------------------------------------
template <int MODE>
__global__ __launch_bounds__(256) void gemm_mfma_abt(
    const ushort* __restrict__ A, const ushort* __restrict__ B,
    const float* __restrict__ bias, float* __restrict__ Cout,
    ushort* __restrict__ qkb, ushort* __restrict__ vtb,
    int M, int N, int K)
{
    __shared__ ushort Al[128 * 64];
    __shared__ ushort Bl[128 * 64];

    const int tid  = threadIdx.x;
    const int lane = tid & 63;
    const int wave = tid >> 6;
    const int wr   = wave >> 1;
    const int wc   = wave & 1;
    const int l15  = lane & 15;
    const int l4   = lane >> 4;
    const int m0   = blockIdx.y * 128;
    const int n0   = blockIdx.x * 128;

    f32x4 acc[4][4];
#pragma unroll
    for (int m = 0; m < 4; ++m)
#pragma unroll
        for (int n = 0; n < 4; ++n)
#pragma unroll
            for (int r = 0; r < 4; ++r) acc[m][n][r] = 0.f;

    for (int k0 = 0; k0 < K; k0 += 64) {
#pragma unroll
        for (int it = 0; it < 4; ++it) {
            int chunk = tid + it * 256;
            int row = chunk >> 3;
            int kc  = (chunk & 7) * 8;
            gload_lds16(&A[(size_t)(m0 + row) * K + k0 + kc], &Al[chunk * 8]);
            gload_lds16(&B[(size_t)(n0 + row) * K + k0 + kc], &Bl[chunk * 8]);
        }
        __syncthreads();

#pragma unroll
        for (int kk = 0; kk < 2; ++kk) {
            const int ko = kk * 32 + l4 * 8;
            bf16x8 a[4], b[4];
#pragma unroll
            for (int m = 0; m < 4; ++m)
                a[m] = *reinterpret_cast<const bf16x8*>(
                    &Al[(wr * 64 + m * 16 + l15) * 64 + ko]);
#pragma unroll
            for (int n = 0; n < 4; ++n)
                b[n] = *reinterpret_cast<const bf16x8*>(
                    &Bl[(wc * 64 + n * 16 + l15) * 64 + ko]);
            __builtin_amdgcn_s_setprio(1);
#pragma unroll
            for (int m = 0; m < 4; ++m)
#pragma unroll
                for (int n = 0; n < 4; ++n)
                    acc[m][n] = __builtin_amdgcn_mfma_f32_16x16x32_bf16(
                        a[m], b[n], acc[m][n], 0, 0, 0);
            __builtin_amdgcn_s_setprio(0);
        }
        __syncthreads();
    }

    // epilogue; C/D: col = lane&15, row = (lane>>4)*4 + reg (verified)
#pragma unroll
    for (int n = 0; n < 4; ++n) {
        const int col = n0 + wc * 64 + n * 16 + l15;
        const float bv = bias[col];
        if (MODE == 0) {
#pragma unroll
            for (int m = 0; m < 4; ++m) {
                const int row0 = m0 + wr * 64 + m * 16 + l4 * 4;
#pragma unroll
                for (int r = 0; r < 4; ++r)
                    Cout[(size_t)(row0 + r) * N + col] = acc[m][n][r] + bv;
            }
        } else if (col < 2 * EMB) {
            // Q/K part, row-major bf16, stride 2048. Q pre-scaled by BETA.
            const float qs = (col < EMB) ? 0.18033688f : 1.0f;
#pragma unroll
            for (int m = 0; m < 4; ++m) {
                const int row0 = m0 + wr * 64 + m * 16 + l4 * 4;
#pragma unroll
                for (int r = 0; r < 4; ++r)
                    qkb[(size_t)(row0 + r) * 2048 + col] =
                        f2bf((acc[m][n][r] + bv) * qs);
            }
        } else {
            // V part, transposed: vtb[(b*16+h)*64 + d][t], t = row
            const int h = (col - 2 * EMB) >> 6;
            const int d = col & 63;
#pragma unroll
            for (int m = 0; m < 4; ++m) {
                const int row0 = m0 + wr * 64 + m * 16 + l4 * 4;
                const int bb = row0 >> 11;
                const int t  = row0 & 2047;
                uint2 pk;
                pk.x = cvt_pk_bf16(acc[m][n][0] + bv, acc[m][n][1] + bv);
                pk.y = cvt_pk_bf16(acc[m][n][2] + bv, acc[m][n][3] + bv);
                *reinterpret_cast<uint2*>(
                    &vtb[((size_t)(bb * 16 + h) * 64 + d) * 2048 + t]) = pk;
            }
        }
    }
}

// ---------------------------------------------------------------------------
// MFMA flash attention, swapped-QK softmax, UNIFORM-WORK pair blocks,
// oct-buffered K/V, Q pre-scaled (log2-domain scores).
// NEW: in-register P. The swapped-QK^T output fragment (q=lane&15,
// k=n*16+l4*4+r) is exactly the 16x16x16 MFMA A-operand layout for k-block
// n, so exp2+cvt_pk feeds PV directly: no P LDS round-trip. V's K16 B-frags
// via ds_read_b64. Falls back to the LDS path if the builtin is missing.
// ---------------------------------------------------------------------------
__global__ __launch_bounds__(512) void attn_mfma(
    const ushort* __restrict__ qk, const ushort* __restrict__ vt,
    ushort* __restrict__ y)
{
    __shared__ alignas(16) ushort Kl[8][4096];
    __shared__ alignas(16) ushort Vl[8][4096];
    __shared__ alignas(16) ushort QP[8192];     // 128 rows x 64

    const int tid  = threadIdx.x;
    const int lane = tid & 63;
    const int w    = tid >> 6;     // wave 0..7
    const int l15  = lane & 15;
    const int l4   = lane >> 4;

    // block -> (bh, pair): 4 consecutive bh per XCD
    const int id  = blockIdx.x;                   // 0..255
    const int xcd = id & 7;
    const int bh  = xcd * 4 + ((id >> 3) & 3);    // 0..31
    const int pp  = id >> 5;                      // pair 0..7
    const int b   = bh >> 4;
    const int h   = bh & 15;

    const ushort* qbase = qk + (size_t)b * SEQ * 2048 + h * HD;
    const ushort* kbase = qbase + EMB;
    const ushort* vbase = vt + (size_t)bh * HD * SEQ;        // [d][t]

    const int swz   = (l15 & 7) << 4;
    const int koff0 = ((l4 * 16) ^ swz) >> 1;        // ushort units
    const int koff1 = ((64 + l4 * 16) ^ swz) >> 1;

#if !HAVE_MFMA16
    int pso[4];
#pragma unroll
    for (int n = 0; n < 4; ++n) pso[n] = ((n * 32 + l4 * 8) ^ swz) >> 1;
    const short OBF = (short)0x3F80;
    const bf16x8 ones = {OBF, OBF, OBF, OBF, OBF, OBF, OBF, OBF};
#else
    // K16 V-frag offsets (ushort units): k-block n -> bytes (n*32+l4*8)^swz
    int voff[4];
#pragma unroll
    for (int n = 0; n < 4; ++n) voff[n] = ((n * 32 + l4 * 8) ^ swz) >> 1;
    const short OBF = (short)0x3F80;
    const bf16x4 ones4 = {OBF, OBF, OBF, OBF};
#endif

    const int qrow = (w * 16 + l15) * 64;    // wave-local Q/P row base

    // staging coordinates (one 16B chunk per thread per 64x64 tile)
    const int sr = tid >> 3;                          // row 0..63
    const int sc = ((tid & 7) ^ (sr & 7)) << 3;       // swizzled col
    const int i2 = tid + 512;
    const int qr2 = i2 >> 3;
    const int qc2 = ((i2 & 7) ^ (qr2 & 7)) << 3;

#pragma unroll
    for (int pass = 0; pass < 2; ++pass) {
        const int qt  = pass ? (15 - pp) : pp;
        const int nkv = 2 * qt + 2;

        // ---- prologue: stage Q (128x64) + kv tiles 0..3 ----
        gload_lds16(qbase + (size_t)(qt * 128 + sr) * 2048 + sc, &QP[tid * 8]);
        gload_lds16(qbase + (size_t)(qt * 128 + qr2) * 2048 + qc2, &QP[i2 * 8]);
#pragma unroll
        for (int t = 0; t < 4; ++t) {
            gload_lds16(kbase + (size_t)(t * 64 + sr) * 2048 + sc, &Kl[t][tid * 8]);
            gload_lds16(vbase + (size_t)sr * 2048 + t * 64 + sc, &Vl[t][tid * 8]);
        }
        __syncthreads();

        const bf16x8 qf0 = *reinterpret_cast<const bf16x8*>(&QP[qrow + koff0]);
        const bf16x8 qf1 = *reinterpret_cast<const bf16x8*>(&QP[qrow + koff1]);

        f32x4 o[4];
#pragma unroll
        for (int n = 0; n < 4; ++n)
#pragma unroll
            for (int r = 0; r < 4; ++r) o[n][r] = 0.f;
        f32x4 lacc = {0.f, 0.f, 0.f, 0.f};
        float m = -3.0e38f;

        auto computeTile = [&](const ushort* Kb, const ushort* Vb, int kkt) {
            bf16x8 kf[4][2];
#pragma unroll
            for (int n = 0; n < 4; ++n) {
                kf[n][0] = *reinterpret_cast<const bf16x8*>(
                    &Kb[(n * 16 + l15) * 64 + koff0]);
                kf[n][1] = *reinterpret_cast<const bf16x8*>(
                    &Kb[(n * 16 + l15) * 64 + koff1]);
            }
            f32x4 s[4];
            __builtin_amdgcn_s_setprio(1);
#pragma unroll
            for (int n = 0; n < 4; ++n) {
                f32x4 z = {0.f, 0.f, 0.f, 0.f};
                z = __builtin_amdgcn_mfma_f32_16x16x32_bf16(kf[n][0], qf0, z, 0, 0, 0);
                s[n] = __builtin_amdgcn_mfma_f32_16x16x32_bf16(kf[n][1], qf1, z, 0, 0, 0);
            }
            __builtin_amdgcn_s_setprio(0);

#if HAVE_MFMA16
            // V K16 B-fragments: row d = dblk*16+l15, k = n*16 + l4*4 + i
            bf16x4 vf16[4][4];
#pragma unroll
            for (int d = 0; d < 4; ++d)
#pragma unroll
                for (int n = 0; n < 4; ++n)
                    vf16[d][n] = *reinterpret_cast<const bf16x4*>(
                        &Vb[(d * 16 + l15) * 64 + voff[n]]);
#else
            bf16x8 vf[4][2];
#pragma unroll
            for (int n = 0; n < 4; ++n) {
                vf[n][0] = *reinterpret_cast<const bf16x8*>(
                    &Vb[(n * 16 + l15) * 64 + koff0]);
                vf[n][1] = *reinterpret_cast<const bf16x8*>(
                    &Vb[(n * 16 + l15) * 64 + koff1]);
            }
#endif

            // causal mask: only the last two kv tiles can violate causality
            if (kkt >= nkv - 2) {
                const int q0 = qt * 128 + w * 16 + l15;
#pragma unroll
                for (int n = 0; n < 4; ++n)
#pragma unroll
                    for (int r = 0; r < 4; ++r) {
                        int kg = kkt * 64 + n * 16 + l4 * 4 + r;
                        if (kg > q0) s[n][r] = -3.0e38f;
                    }
            }

            // per-lane partial max (tree); scores already log2-domain
            float a0 = fmaxf(fmaxf(s[0][0], s[0][1]), fmaxf(s[0][2], s[0][3]));
            float a1 = fmaxf(fmaxf(s[1][0], s[1][1]), fmaxf(s[1][2], s[1][3]));
            float a2 = fmaxf(fmaxf(s[2][0], s[2][1]), fmaxf(s[2][2], s[2][3]));
            float a3 = fmaxf(fmaxf(s[3][0], s[3][1]), fmaxf(s[3][2], s[3][3]));
            float pm = fmaxf(fmaxf(a0, a1), fmaxf(a2, a3));

            // defer-max rescale (rare, wave-uniform); ballot covers all (k,q)
            if (__any(pm > m + 8.0f)) {
                float tm = fmaxf(pm, __shfl_xor(pm, 16));
                tm = fmaxf(tm, __shfl_xor(tm, 32));
                float mn = fmaxf(m, tm);
                float al = exp2f(m - mn);
                m = mn;
                float b0 = __shfl(al, l4 * 4 + 0, 16);
                float b1 = __shfl(al, l4 * 4 + 1, 16);
                float b2 = __shfl(al, l4 * 4 + 2, 16);
                float b3 = __shfl(al, l4 * 4 + 3, 16);
                lacc[0] *= b0; lacc[1] *= b1; lacc[2] *= b2; lacc[3] *= b3;
#pragma unroll
                for (int n = 0; n < 4; ++n) {
                    o[n][0] *= b0; o[n][1] *= b1; o[n][2] *= b2; o[n][3] *= b3;
                }
            }

#if HAVE_MFMA16
            // p = 2^(s - m) packed in-register: pfr[n] IS the K16 A-fragment
            bf16x4 pfr[4];
#pragma unroll
            for (int n = 0; n < 4; ++n) {
                float pa = exp2f(s[n][0] - m);
                float pb = exp2f(s[n][1] - m);
                float pc = exp2f(s[n][2] - m);
                float pd = exp2f(s[n][3] - m);
                uint2 t;
                t.x = cvt_pk_bf16(pa, pb);
                t.y = cvt_pk_bf16(pc, pd);
                pfr[n] = *reinterpret_cast<bf16x4*>(&t);
            }

            // O += P V (16 x K16 MFMA), l += P·1 (4 x K16)
            __builtin_amdgcn_s_setprio(1);
#pragma unroll
            for (int n = 0; n < 4; ++n) {
                lacc = __builtin_amdgcn_mfma_f32_16x16x16bf16_1k(
                    pfr[n], ones4, lacc, 0, 0, 0);
#pragma unroll
                for (int d = 0; d < 4; ++d)
                    o[d] = __builtin_amdgcn_mfma_f32_16x16x16bf16_1k(
                        pfr[n], vf16[d][n], o[d], 0, 0, 0);
            }
            __builtin_amdgcn_s_setprio(0);
#else
            // fallback: P through LDS (round-13 path)
#pragma unroll
            for (int n = 0; n < 4; ++n) {
                float pa = exp2f(s[n][0] - m);
                float pb = exp2f(s[n][1] - m);
                float pc = exp2f(s[n][2] - m);
                float pd = exp2f(s[n][3] - m);
                uint2 pk;
                pk.x = cvt_pk_bf16(pa, pb);
                pk.y = cvt_pk_bf16(pc, pd);
                *reinterpret_cast<uint2*>(&QP[qrow + pso[n]]) = pk;
            }
            bf16x8 pf0 = *reinterpret_cast<const bf16x8*>(&QP[qrow + koff0]);
            bf16x8 pf1 = *reinterpret_cast<const bf16x8*>(&QP[qrow + koff1]);
            __builtin_amdgcn_s_setprio(1);
            lacc = __builtin_amdgcn_mfma_f32_16x16x32_bf16(pf0, ones, lacc, 0, 0, 0);
            lacc = __builtin_amdgcn_mfma_f32_16x16x32_bf16(pf1, ones, lacc, 0, 0, 0);
#pragma unroll
            for (int n = 0; n < 4; ++n) {
                o[n] = __builtin_amdgcn_mfma_f32_16x16x32_bf16(pf0, vf[n][0], o[n], 0, 0, 0);
                o[n] = __builtin_amdgcn_mfma_f32_16x16x32_bf16(pf1, vf[n][1], o[n], 0, 0, 0);
            }
            __builtin_amdgcn_s_setprio(0);
#endif
        };

        // ---- main loop: 4 tiles per barrier window ----
        for (int kk = 0; kk < nkv; kk += 4) {
            // stage window kk+4..kk+7 (slots t&7, disjoint from compute slots)
#pragma unroll
            for (int j = 0; j < 4; ++j) {
                int t = kk + 4 + j;
                if (t < nkv) {
                    gload_lds16(kbase + (size_t)(t * 64 + sr) * 2048 + sc,
                                &Kl[t & 7][tid * 8]);
                    gload_lds16(vbase + (size_t)sr * 2048 + t * 64 + sc,
                                &Vl[t & 7][tid * 8]);
                }
            }
            // compute tiles kk..kk+3
#pragma unroll
            for (int j = 0; j < 4; ++j) {
                int t = kk + j;
                if (t < nkv) computeTile(Kl[t & 7], Vl[t & 7], t);
            }
            __syncthreads();
        }

        // epilogue: O rows q = w*16 + l4*4 + r, cols d = n*16 + l15
#pragma unroll
        for (int r = 0; r < 4; ++r) {
            float inv = 1.f / lacc[r];
            int row = qt * 128 + w * 16 + l4 * 4 + r;
#pragma unroll
            for (int n = 0; n < 4; ++n) {
                y[(size_t)(b * SEQ + row) * EMB + h * HD + n * 16 + l15] =
                    f2bf(o[n][r] * inv);
            }
        }
        __syncthreads();   // LDS safe before next pass's prologue
    }
}

// ---------------------------------------------------------------------------
extern "C" void kernel_launch(void* const* d_in, const int* in_sizes, int n_in,
                              void* d_out, int out_size, void* d_ws, size_t ws_size,
                              hipStream_t stream)
{
    const float* x     = (const float*)d_in[0];   // [B,T,E]
    const float* qkv_w = (const float*)d_in[1];   // [3E,E]
    const float* qkv_b = (const float*)d_in[2];   // [3E]
    const float* o_w   = (const float*)d_in[3];   // [E,E]
    const float* o_b   = (const float*)d_in[4];   // [E]
    float* out = (float*)d_out;                   // [B,T,E] fp32

    // workspace (ushort units)
    ushort* xb    = (ushort*)d_ws;                       // 4M
    ushort* wqkvb = xb    + (size_t)M_ROWS * EMB;        // 3M
    ushort* owb   = wqkvb + (size_t)3 * EMB * EMB;       // 1M
    ushort* qkb   = owb   + (size_t)EMB * EMB;           // 8M  [4096][2048]
    ushort* vtb   = qkb   + (size_t)M_ROWS * 2 * EMB;    // 4M  [32][64][2048]
    ushort* ybb   = vtb   + (size_t)32 * HD * SEQ;       // 4M  [4096][1024]

    // 0) fused fp32 -> bf16 (x, qkv_w, o_w -> contiguous xb/wqkvb/owb)
    {
        int n1 = M_ROWS * EMB;        // 4M
        int n2 = 3 * EMB * EMB;       // 3M
        int ntot = n1 + n2 + EMB * EMB;
        cvt3_f32_bf16<<<ntot / 1024, 256, 0, stream>>>(
            x, qkv_w, o_w, xb, n1, n2);
    }

    // 1) QKV projection, split output: Q (BETA-scaled)/K row-major, V transposed
    {
        dim3 grid(3 * EMB / 128, M_ROWS / 128);   // (24, 32)
        gemm_mfma_abt<1><<<grid, 256, 0, stream>>>(
            xb, wqkvb, qkv_b, nullptr, qkb, vtb, M_ROWS, 3 * EMB, EMB);
    }

    // 2) MFMA flash attention -> ybb (bf16 [M,E]); uniform-work blocks
    {
        attn_mfma<<<256, 512, 0, stream>>>(qkb, vtb, ybb);
    }

    // 3) Output projection (fp32 out)
    {
        dim3 grid(EMB / 128, M_ROWS / 128);       // (8, 32)
        gemm_mfma_abt<0><<<grid, 256, 0, stream>>>(
            ybb, owb, o_b, out, nullptr, nullptr, M_ROWS, EMB, EMB);
    }
}

// Round 15
// 113.792 us; speedup vs baseline: 1.0294x; 1.0294x over previous
//
#include <hip/hip_runtime.h>
#include <hip/hip_bf16.h>
#include <math.h>

// Problem constants
#define BATCH 2
#define SEQ   2048
#define EMB   1024
#define NH    16
#define HD    64
#define M_ROWS (BATCH * SEQ)   // 4096

typedef __attribute__((ext_vector_type(8))) short bf16x8;
typedef __attribute__((ext_vector_type(4))) float f32x4;

// fp32 -> bf16 round-to-nearest-even, raw bits
__device__ __forceinline__ ushort f2bf(float f) {
    unsigned u = __float_as_uint(f);
    unsigned lsb = (u >> 16) & 1u;
    u += 0x7fffu + lsb;
    return (ushort)(u >> 16);
}

// packed f32 pair -> 2 bf16 in one u32 (RNE), single VALU op
__device__ __forceinline__ unsigned cvt_pk_bf16(float lo, float hi) {
    unsigned r;
    asm("v_cvt_pk_bf16_f32 %0, %1, %2" : "=v"(r) : "v"(lo), "v"(hi));
    return r;
}

__device__ __forceinline__ void gload_lds16(const void* g, void* l) {
    __builtin_amdgcn_global_load_lds(
        (const __attribute__((address_space(1))) unsigned int*)g,
        (__attribute__((address_space(3))) unsigned int*)l, 16, 0, 0);
}

// ---------------------------------------------------------------------------
// fused fp32 -> bf16 conversion of x, qkv_w, o_w (outputs contiguous in ws)
// ---------------------------------------------------------------------------
__global__ __launch_bounds__(256) void cvt3_f32_bf16(
    const float* __restrict__ s1, const float* __restrict__ s2,
    const float* __restrict__ s3, ushort* __restrict__ out,
    int n1, int n2)
{
    int i = (blockIdx.x * 256 + threadIdx.x) * 4;
    const float* src;
    int off;
    if (i < n1)            { src = s1; off = i; }
    else if (i < n1 + n2)  { src = s2; off = i - n1; }
    else                   { src = s3; off = i - n1 - n2; }
    float4 v = *reinterpret_cast<const float4*>(&src[off]);
    uint2 pk;
    pk.x = cvt_pk_bf16(v.x, v.y);
    pk.y = cvt_pk_bf16(v.z, v.w);
    *reinterpret_cast<uint2*>(&out[i]) = pk;
}

// ---------------------------------------------------------------------------
// bf16 MFMA GEMM: C[M,N] = A[M,K] * B[N,K]^T + bias[N]
// MODE 0: fp32 output to Cout (O-projection).
// MODE 1: QKV split — cols [0,1024) = Q, scaled by BETA=0.125*log2(e);
//         cols [0,2048) bf16 to qkb (stride 2048);
//         cols [2048,3072) = V written TRANSPOSED to vtb[b*16+h][d][t].
// ---------------------------------------------------------------------------
template <int MODE>
__global__ __launch_bounds__(256) void gemm_mfma_abt(
    const ushort* __restrict__ A, const ushort* __restrict__ B,
    const float* __restrict__ bias, float* __restrict__ Cout,
    ushort* __restrict__ qkb, ushort* __restrict__ vtb,
    int M, int N, int K)
{
    __shared__ ushort Al[128 * 64];
    __shared__ ushort Bl[128 * 64];

    const int tid  = threadIdx.x;
    const int lane = tid & 63;
    const int wave = tid >> 6;
    const int wr   = wave >> 1;
    const int wc   = wave & 1;
    const int l15  = lane & 15;
    const int l4   = lane >> 4;
    const int m0   = blockIdx.y * 128;
    const int n0   = blockIdx.x * 128;

    f32x4 acc[4][4];
#pragma unroll
    for (int m = 0; m < 4; ++m)
#pragma unroll
        for (int n = 0; n < 4; ++n)
#pragma unroll
            for (int r = 0; r < 4; ++r) acc[m][n][r] = 0.f;

    for (int k0 = 0; k0 < K; k0 += 64) {
#pragma unroll
        for (int it = 0; it < 4; ++it) {
            int chunk = tid + it * 256;
            int row = chunk >> 3;
            int kc  = (chunk & 7) * 8;
            gload_lds16(&A[(size_t)(m0 + row) * K + k0 + kc], &Al[chunk * 8]);
            gload_lds16(&B[(size_t)(n0 + row) * K + k0 + kc], &Bl[chunk * 8]);
        }
        __syncthreads();

#pragma unroll
        for (int kk = 0; kk < 2; ++kk) {
            const int ko = kk * 32 + l4 * 8;
            bf16x8 a[4], b[4];
#pragma unroll
            for (int m = 0; m < 4; ++m)
                a[m] = *reinterpret_cast<const bf16x8*>(
                    &Al[(wr * 64 + m * 16 + l15) * 64 + ko]);
#pragma unroll
            for (int n = 0; n < 4; ++n)
                b[n] = *reinterpret_cast<const bf16x8*>(
                    &Bl[(wc * 64 + n * 16 + l15) * 64 + ko]);
            __builtin_amdgcn_s_setprio(1);
#pragma unroll
            for (int m = 0; m < 4; ++m)
#pragma unroll
                for (int n = 0; n < 4; ++n)
                    acc[m][n] = __builtin_amdgcn_mfma_f32_16x16x32_bf16(
                        a[m], b[n], acc[m][n], 0, 0, 0);
            __builtin_amdgcn_s_setprio(0);
        }
        __syncthreads();
    }

    // epilogue; C/D: col = lane&15, row = (lane>>4)*4 + reg (verified)
#pragma unroll
    for (int n = 0; n < 4; ++n) {
        const int col = n0 + wc * 64 + n * 16 + l15;
        const float bv = bias[col];
        if (MODE == 0) {
#pragma unroll
            for (int m = 0; m < 4; ++m) {
                const int row0 = m0 + wr * 64 + m * 16 + l4 * 4;
#pragma unroll
                for (int r = 0; r < 4; ++r)
                    Cout[(size_t)(row0 + r) * N + col] = acc[m][n][r] + bv;
            }
        } else if (col < 2 * EMB) {
            // Q/K part, row-major bf16, stride 2048. Q pre-scaled by BETA.
            const float qs = (col < EMB) ? 0.18033688f : 1.0f;
#pragma unroll
            for (int m = 0; m < 4; ++m) {
                const int row0 = m0 + wr * 64 + m * 16 + l4 * 4;
#pragma unroll
                for (int r = 0; r < 4; ++r)
                    qkb[(size_t)(row0 + r) * 2048 + col] =
                        f2bf((acc[m][n][r] + bv) * qs);
            }
        } else {
            // V part, transposed: vtb[(b*16+h)*64 + d][t], t = row
            const int h = (col - 2 * EMB) >> 6;
            const int d = col & 63;
#pragma unroll
            for (int m = 0; m < 4; ++m) {
                const int row0 = m0 + wr * 64 + m * 16 + l4 * 4;
                const int bb = row0 >> 11;
                const int t  = row0 & 2047;
                uint2 pk;
                pk.x = cvt_pk_bf16(acc[m][n][0] + bv, acc[m][n][1] + bv);
                pk.y = cvt_pk_bf16(acc[m][n][2] + bv, acc[m][n][3] + bv);
                *reinterpret_cast<uint2*>(
                    &vtb[((size_t)(bb * 16 + h) * 64 + d) * 2048 + t]) = pk;
            }
        }
    }
}

// ---------------------------------------------------------------------------
// MFMA flash attention, swapped-QK softmax. UNIFORM-WORK pair blocks (512
// thr, 8 waves, 1 block/CU; block = (bh, pair p) processing qt=p then 15-p,
// 34 kv-tiles total). Q pre-scaled (log2-domain scores).
// PAIRED-TILE INTERLEAVE: each loop body computes tiles kk and kk+1 with
// both S^T MFMA clusters issued back-to-back (independent), then
// softmaxA -> PV_A -> softmaxB -> PV_B. A and B use DISJOINT P regions
// (QP rows 0..127 / 128..255) so B's exp2/pack/stores overlap PV_A with
// no write-after-read hazard. Quad-buffered K/V, 2 tiles staged per barrier.
// Critical-path-lean softmax (per-lane partial max + ballot; l via MFMA-ones).
// ---------------------------------------------------------------------------
__global__ __launch_bounds__(512) void attn_mfma(
    const ushort* __restrict__ qk, const ushort* __restrict__ vt,
    ushort* __restrict__ y)
{
    __shared__ alignas(16) ushort Kl[4][4096];
    __shared__ alignas(16) ushort Vl[4][4096];
    __shared__ alignas(16) ushort QP[16384];    // rows 0..127: Q then P_A; 128..255: P_B

    const int tid  = threadIdx.x;
    const int lane = tid & 63;
    const int w    = tid >> 6;     // wave 0..7
    const int l15  = lane & 15;
    const int l4   = lane >> 4;

    // block -> (bh, pair): 4 consecutive bh per XCD
    const int id  = blockIdx.x;                   // 0..255
    const int xcd = id & 7;
    const int bh  = xcd * 4 + ((id >> 3) & 3);    // 0..31
    const int pp  = id >> 5;                      // pair 0..7
    const int b   = bh >> 4;
    const int h   = bh & 15;

    const ushort* qbase = qk + (size_t)b * SEQ * 2048 + h * HD;
    const ushort* kbase = qbase + EMB;
    const ushort* vbase = vt + (size_t)bh * HD * SEQ;        // [d][t]

    const int swz   = (l15 & 7) << 4;
    const int koff0 = ((l4 * 16) ^ swz) >> 1;        // ushort units
    const int koff1 = ((64 + l4 * 16) ^ swz) >> 1;

    int pso[4];
#pragma unroll
    for (int n = 0; n < 4; ++n) pso[n] = ((n * 32 + l4 * 8) ^ swz) >> 1;

    const short OBF = (short)0x3F80;   // 1.0 bf16
    const bf16x8 ones = {OBF, OBF, OBF, OBF, OBF, OBF, OBF, OBF};

    const int qrowA = (w * 16 + l15) * 64;          // Q / P_A row base
    const int qrowB = qrowA + 128 * 64;             // P_B row base (disjoint)

    // staging coordinates (one 16B chunk per thread per 64x64 tile)
    const int sr = tid >> 3;                          // row 0..63
    const int sc = ((tid & 7) ^ (sr & 7)) << 3;       // swizzled col
    const int i2 = tid + 512;
    const int qr2 = i2 >> 3;
    const int qc2 = ((i2 & 7) ^ (qr2 & 7)) << 3;

#pragma unroll
    for (int pass = 0; pass < 2; ++pass) {
        const int qt  = pass ? (15 - pp) : pp;
        const int nkv = 2 * qt + 2;                   // even

        // ---- prologue: stage Q (128x64, rows 0..127) + kv tiles 0,1 ----
        gload_lds16(qbase + (size_t)(qt * 128 + sr) * 2048 + sc, &QP[tid * 8]);
        gload_lds16(qbase + (size_t)(qt * 128 + qr2) * 2048 + qc2, &QP[i2 * 8]);
        gload_lds16(kbase + (size_t)sr * 2048 + sc, &Kl[0][tid * 8]);
        gload_lds16(kbase + (size_t)(64 + sr) * 2048 + sc, &Kl[1][tid * 8]);
        gload_lds16(vbase + (size_t)sr * 2048 + sc, &Vl[0][tid * 8]);
        gload_lds16(vbase + (size_t)sr * 2048 + 64 + sc, &Vl[1][tid * 8]);
        __syncthreads();

        const bf16x8 qf0 = *reinterpret_cast<const bf16x8*>(&QP[qrowA + koff0]);
        const bf16x8 qf1 = *reinterpret_cast<const bf16x8*>(&QP[qrowA + koff1]);

        f32x4 o[4];
#pragma unroll
        for (int n = 0; n < 4; ++n)
#pragma unroll
            for (int r = 0; r < 4; ++r) o[n][r] = 0.f;
        f32x4 lacc = {0.f, 0.f, 0.f, 0.f};
        float m = -3.0e38f;

        const int q0g = qt * 128 + w * 16 + l15;      // this wave's causal bound

        // softmax + PV for one tile's scores (P region given by prow)
        auto softmaxPV = [&](f32x4 (&s)[4], const bf16x8 vf[4][2], int prow) {
            // per-lane partial max (tree); scores already log2-domain
            float a0 = fmaxf(fmaxf(s[0][0], s[0][1]), fmaxf(s[0][2], s[0][3]));
            float a1 = fmaxf(fmaxf(s[1][0], s[1][1]), fmaxf(s[1][2], s[1][3]));
            float a2 = fmaxf(fmaxf(s[2][0], s[2][1]), fmaxf(s[2][2], s[2][3]));
            float a3 = fmaxf(fmaxf(s[3][0], s[3][1]), fmaxf(s[3][2], s[3][3]));
            float pm = fmaxf(fmaxf(a0, a1), fmaxf(a2, a3));

            // defer-max rescale (rare, wave-uniform); ballot covers all (k,q)
            if (__any(pm > m + 8.0f)) {
                float tm = fmaxf(pm, __shfl_xor(pm, 16));
                tm = fmaxf(tm, __shfl_xor(tm, 32));
                float mn = fmaxf(m, tm);
                float al = exp2f(m - mn);
                m = mn;
                float b0 = __shfl(al, l4 * 4 + 0, 16);
                float b1 = __shfl(al, l4 * 4 + 1, 16);
                float b2 = __shfl(al, l4 * 4 + 2, 16);
                float b3 = __shfl(al, l4 * 4 + 3, 16);
                lacc[0] *= b0; lacc[1] *= b1; lacc[2] *= b2; lacc[3] *= b3;
#pragma unroll
                for (int n = 0; n < 4; ++n) {
                    o[n][0] *= b0; o[n][1] *= b1; o[n][2] *= b2; o[n][3] *= b3;
                }
            }

            // p = 2^(s - m), pack + store P (this tile's region)
#pragma unroll
            for (int n = 0; n < 4; ++n) {
                float pa = exp2f(s[n][0] - m);
                float pb = exp2f(s[n][1] - m);
                float pc = exp2f(s[n][2] - m);
                float pd = exp2f(s[n][3] - m);
                uint2 pk;
                pk.x = cvt_pk_bf16(pa, pb);
                pk.y = cvt_pk_bf16(pc, pd);
                *reinterpret_cast<uint2*>(&QP[prow + pso[n]]) = pk;
            }

            // O += P V, l += P·1
            bf16x8 pf0 = *reinterpret_cast<const bf16x8*>(&QP[prow + koff0]);
            bf16x8 pf1 = *reinterpret_cast<const bf16x8*>(&QP[prow + koff1]);
            __builtin_amdgcn_s_setprio(1);
            lacc = __builtin_amdgcn_mfma_f32_16x16x32_bf16(pf0, ones, lacc, 0, 0, 0);
            lacc = __builtin_amdgcn_mfma_f32_16x16x32_bf16(pf1, ones, lacc, 0, 0, 0);
#pragma unroll
            for (int n = 0; n < 4; ++n) {
                o[n] = __builtin_amdgcn_mfma_f32_16x16x32_bf16(pf0, vf[n][0], o[n], 0, 0, 0);
                o[n] = __builtin_amdgcn_mfma_f32_16x16x32_bf16(pf1, vf[n][1], o[n], 0, 0, 0);
            }
            __builtin_amdgcn_s_setprio(0);
        };

        // ---- main loop: 2 tiles per iteration, paired interleave ----
        for (int kk = 0; kk < nkv; kk += 2) {
            // stage tiles kk+2, kk+3 (slots disjoint from compute slots)
            if (kk + 2 < nkv) {
                const int b2 = (kk + 2) & 3;
                const int b3 = (kk + 3) & 3;
                gload_lds16(kbase + (size_t)((kk + 2) * 64 + sr) * 2048 + sc,
                            &Kl[b2][tid * 8]);
                gload_lds16(kbase + (size_t)((kk + 3) * 64 + sr) * 2048 + sc,
                            &Kl[b3][tid * 8]);
                gload_lds16(vbase + (size_t)sr * 2048 + (kk + 2) * 64 + sc,
                            &Vl[b2][tid * 8]);
                gload_lds16(vbase + (size_t)sr * 2048 + (kk + 3) * 64 + sc,
                            &Vl[b3][tid * 8]);
            }

            const ushort* KbA = Kl[kk & 3];
            const ushort* KbB = Kl[(kk + 1) & 3];
            const ushort* VbA = Vl[kk & 3];
            const ushort* VbB = Vl[(kk + 1) & 3];

            // both tiles' K fragments + S^T MFMAs back-to-back (independent)
            bf16x8 kfA[4][2], kfB[4][2];
#pragma unroll
            for (int n = 0; n < 4; ++n) {
                kfA[n][0] = *reinterpret_cast<const bf16x8*>(
                    &KbA[(n * 16 + l15) * 64 + koff0]);
                kfA[n][1] = *reinterpret_cast<const bf16x8*>(
                    &KbA[(n * 16 + l15) * 64 + koff1]);
                kfB[n][0] = *reinterpret_cast<const bf16x8*>(
                    &KbB[(n * 16 + l15) * 64 + koff0]);
                kfB[n][1] = *reinterpret_cast<const bf16x8*>(
                    &KbB[(n * 16 + l15) * 64 + koff1]);
            }
            f32x4 sA[4], sB[4];
            __builtin_amdgcn_s_setprio(1);
#pragma unroll
            for (int n = 0; n < 4; ++n) {
                f32x4 zA = {0.f, 0.f, 0.f, 0.f};
                zA = __builtin_amdgcn_mfma_f32_16x16x32_bf16(kfA[n][0], qf0, zA, 0, 0, 0);
                sA[n] = __builtin_amdgcn_mfma_f32_16x16x32_bf16(kfA[n][1], qf1, zA, 0, 0, 0);
                f32x4 zB = {0.f, 0.f, 0.f, 0.f};
                zB = __builtin_amdgcn_mfma_f32_16x16x32_bf16(kfB[n][0], qf0, zB, 0, 0, 0);
                sB[n] = __builtin_amdgcn_mfma_f32_16x16x32_bf16(kfB[n][1], qf1, zB, 0, 0, 0);
            }
            __builtin_amdgcn_s_setprio(0);

            // both tiles' V fragments (issue early; latency hides under softmax)
            bf16x8 vfA[4][2], vfB[4][2];
#pragma unroll
            for (int n = 0; n < 4; ++n) {
                vfA[n][0] = *reinterpret_cast<const bf16x8*>(
                    &VbA[(n * 16 + l15) * 64 + koff0]);
                vfA[n][1] = *reinterpret_cast<const bf16x8*>(
                    &VbA[(n * 16 + l15) * 64 + koff1]);
                vfB[n][0] = *reinterpret_cast<const bf16x8*>(
                    &VbB[(n * 16 + l15) * 64 + koff0]);
                vfB[n][1] = *reinterpret_cast<const bf16x8*>(
                    &VbB[(n * 16 + l15) * 64 + koff1]);
            }

            // causal masks (only the last two kv tiles can violate causality)
            if (kk >= nkv - 2) {          // kk == nkv-2: tile A=nkv-2, B=nkv-1
#pragma unroll
                for (int n = 0; n < 4; ++n)
#pragma unroll
                    for (int r = 0; r < 4; ++r) {
                        int kgA = kk * 64 + n * 16 + l4 * 4 + r;
                        if (kgA > q0g)      sA[n][r] = -3.0e38f;
                        if (kgA + 64 > q0g) sB[n][r] = -3.0e38f;
                    }
            }

            // ordered online softmax + PV: A then B (disjoint P regions)
            softmaxPV(sA, vfA, qrowA);
            softmaxPV(sB, vfB, qrowB);
            __syncthreads();
        }

        // epilogue: O rows q = w*16 + l4*4 + r, cols d = n*16 + l15
#pragma unroll
        for (int r = 0; r < 4; ++r) {
            float inv = 1.f / lacc[r];
            int row = qt * 128 + w * 16 + l4 * 4 + r;
#pragma unroll
            for (int n = 0; n < 4; ++n) {
                y[(size_t)(b * SEQ + row) * EMB + h * HD + n * 16 + l15] =
                    f2bf(o[n][r] * inv);
            }
        }
        __syncthreads();   // LDS safe before next pass's prologue
    }
}

// ---------------------------------------------------------------------------
extern "C" void kernel_launch(void* const* d_in, const int* in_sizes, int n_in,
                              void* d_out, int out_size, void* d_ws, size_t ws_size,
                              hipStream_t stream)
{
    const float* x     = (const float*)d_in[0];   // [B,T,E]
    const float* qkv_w = (const float*)d_in[1];   // [3E,E]
    const float* qkv_b = (const float*)d_in[2];   // [3E]
    const float* o_w   = (const float*)d_in[3];   // [E,E]
    const float* o_b   = (const float*)d_in[4];   // [E]
    float* out = (float*)d_out;                   // [B,T,E] fp32

    // workspace (ushort units)
    ushort* xb    = (ushort*)d_ws;                       // 4M
    ushort* wqkvb = xb    + (size_t)M_ROWS * EMB;        // 3M
    ushort* owb   = wqkvb + (size_t)3 * EMB * EMB;       // 1M
    ushort* qkb   = owb   + (size_t)EMB * EMB;           // 8M  [4096][2048]
    ushort* vtb   = qkb   + (size_t)M_ROWS * 2 * EMB;    // 4M  [32][64][2048]
    ushort* ybb   = vtb   + (size_t)32 * HD * SEQ;       // 4M  [4096][1024]

    // 0) fused fp32 -> bf16 (x, qkv_w, o_w -> contiguous xb/wqkvb/owb)
    {
        int n1 = M_ROWS * EMB;        // 4M
        int n2 = 3 * EMB * EMB;       // 3M
        int ntot = n1 + n2 + EMB * EMB;
        cvt3_f32_bf16<<<ntot / 1024, 256, 0, stream>>>(
            x, qkv_w, o_w, xb, n1, n2);
    }

    // 1) QKV projection, split output: Q (BETA-scaled)/K row-major, V transposed
    {
        dim3 grid(3 * EMB / 128, M_ROWS / 128);   // (24, 32)
        gemm_mfma_abt<1><<<grid, 256, 0, stream>>>(
            xb, wqkvb, qkv_b, nullptr, qkb, vtb, M_ROWS, 3 * EMB, EMB);
    }

    // 2) MFMA flash attention -> ybb (bf16 [M,E]); uniform-work pair blocks
    {
        attn_mfma<<<256, 512, 0, stream>>>(qkb, vtb, ybb);
    }

    // 3) Output projection (fp32 out)
    {
        dim3 grid(EMB / 128, M_ROWS / 128);       // (8, 32)
        gemm_mfma_abt<0><<<grid, 256, 0, stream>>>(
            ybb, owb, o_b, out, nullptr, nullptr, M_ROWS, EMB, EMB);
    }
}